// Round 5
// baseline (189.958 us; speedup 1.0000x reference)
//
#include <hip/hip_runtime.h>

#define E 2
#define N 512
#define B 64
#define T 12
#define K 64
#define NB 4

// ---- DPP wave-64 sum (VALU pipe, no DS traffic), result broadcast via readlane
template<int CTRL, int RM>
__device__ __forceinline__ float dpp_add(float x) {
    int y = __builtin_amdgcn_update_dpp(0, __float_as_int(x), CTRL, RM, 0xf, true);
    return x + __int_as_float(y);
}
__device__ __forceinline__ float wave_sum64(float x) {
    x = dpp_add<0x111, 0xf>(x);   // row_shr:1
    x = dpp_add<0x112, 0xf>(x);   // row_shr:2
    x = dpp_add<0x114, 0xf>(x);   // row_shr:4
    x = dpp_add<0x118, 0xf>(x);   // row_shr:8
    x = dpp_add<0x142, 0xa>(x);   // row_bcast:15
    x = dpp_add<0x143, 0xc>(x);   // row_bcast:31
    return __int_as_float(__builtin_amdgcn_readlane(__float_as_int(x), 63));
}

// Fused prep: blocks [0,256) compute sup (4 n-rows/block); blocks [256,320) nodes.
__global__ __launch_bounds__(512)
void k_prep(const float* __restrict__ supports, const float* __restrict__ uu,
            const float* __restrict__ ss, const float* __restrict__ vv,
            const float* __restrict__ bias, const float* __restrict__ inp,
            float* __restrict__ sup, float* __restrict__ nodes) {
    const int blk = blockIdx.x;
    const int tid = threadIdx.x;
    if (blk < 2 * (N / NB)) {
        const int e = blk >> 7;
        const int n0 = (blk & 127) * NB;
        __shared__ float uls[NB][K];
        if (tid < NB * K) {
            const int j = tid >> 6, k = tid & 63;
            float bb = bias[e * K + k];
            float sp_ = (bb > 0.f) ? (bb + log1pf(expf(-bb))) : log1pf(expf(bb));
            uls[j][k] = uu[(size_t)(e * N + n0 + j) * K + k] * ss[e * K + k] * sp_;
        }
        __syncthreads();
        const int m = tid;
        const float4* vp = reinterpret_cast<const float4*>(vv + (size_t)(e * N + m) * K);
        float accs[NB] = {0.f, 0.f, 0.f, 0.f};
#pragma unroll
        for (int i = 0; i < 16; ++i) {
            float4 q = vp[i];
#pragma unroll
            for (int j = 0; j < NB; ++j) {
                const float* w = &uls[j][i * 4];
                accs[j] += w[0] * q.x + w[1] * q.y + w[2] * q.z + w[3] * q.w;
            }
        }
#pragma unroll
        for (int j = 0; j < NB; ++j) {
            const size_t o = (size_t)(e * N + n0 + j) * N + m;
            sup[o] = accs[j] + supports[o];
        }
    } else {
        const int idx = (blk - 2 * (N / NB)) * 512 + tid;  // b*N + n
        const int b = idx >> 9, n = idx & (N - 1);
        float x[T];
        float sq = 0.f;
#pragma unroll
        for (int t = 0; t < T; ++t) {
            float xv = inp[((size_t)(b * T + t) * N + n) * 2];
            x[t] = xv;
            sq += xv * xv;
        }
        float inv = 1.f / fmaxf(sqrtf(sq), 1e-12f);
#pragma unroll
        for (int t = 0; t < T; ++t) nodes[(size_t)idx * T + t] = x[t] * inv;
    }
}

// Thread t: row j = t>>7 (wave-uniform), cols m = 4*(t&127)..+3.
// float4 loads/stores throughout; anchor row via scalar loads; 1 barrier/block.
__global__ __launch_bounds__(512)
void k_main(const float* __restrict__ sup, const float* __restrict__ nodes,
            float* __restrict__ out) {
    const int bi = blockIdx.x;       // B * (N/NB) = 8192
    const int b = bi >> 7;
    const int n0 = (bi & 127) * NB;
    const int t = threadIdx.x;
    const int g = __builtin_amdgcn_readfirstlane(t >> 7);  // 0..3, wave-uniform row
    const int m0 = (t & 127) * 4;
    const int wave = t >> 6, lane = t & 63;

    __shared__ float red[8][2];

    // anchor row n0+g: wave-uniform -> scalar loads
    const float* __restrict__ anc = nodes + ((size_t)(b * N) + n0 + g) * T;
    float a[T];
#pragma unroll
    for (int i = 0; i < T; ++i) a[i] = anc[i];

    // 4 consecutive node rows (48 floats = 192 B contiguous)
    const float4* np4 = reinterpret_cast<const float4*>(nodes + ((size_t)(b * N) + m0) * T);
    float4 nr[12];
#pragma unroll
    for (int i = 0; i < 12; ++i) nr[i] = np4[i];
    const float* x = reinterpret_cast<const float*>(nr);

    // sup row slices, both e (float4, coalesced)
    float4 s0 = *reinterpret_cast<const float4*>(sup + (size_t)(n0 + g) * N + m0);
    float4 s1 = *reinterpret_cast<const float4*>(sup + (size_t)N * N + (size_t)(n0 + g) * N + m0);
    const float* sp0 = reinterpret_cast<const float*>(&s0);
    const float* sp1 = reinterpret_cast<const float*>(&s1);

    float v0[4], v1[4];
    float ls0 = 0.f, ls1 = 0.f;
#pragma unroll
    for (int k = 0; k < 4; ++k) {
        float d2 = 0.f;
#pragma unroll
        for (int i = 0; i < T; ++i) {
            float d = x[k * T + i] - a[i];
            d2 += d * d;
        }
        float dist = (d2 > 0.f) ? sqrtf(d2) : 0.f;
        float f = __expf(-dist) + 1.f;
        v0[k] = fmaxf(sp0[k] * f, 0.f);
        v1[k] = fmaxf(sp1[k] * f, 0.f);
        ls0 += v0[k];
        ls1 += v1[k];
    }

    float w0 = wave_sum64(ls0);
    float w1 = wave_sum64(ls1);
    if (lane == 0) { red[wave][0] = w0; red[wave][1] = w1; }
    __syncthreads();

    // group g = waves 2g, 2g+1; every thread combines the two partials itself
    float inv0 = 1.f / fmaxf(red[2 * g][0] + red[2 * g + 1][0], 1e-12f);
    float inv1 = 1.f / fmaxf(red[2 * g][1] + red[2 * g + 1][1], 1e-12f);

    float4 o0 = make_float4(v0[0] * inv0, v0[1] * inv0, v0[2] * inv0, v0[3] * inv0);
    float4 o1 = make_float4(v1[0] * inv1, v1[1] * inv1, v1[2] * inv1, v1[3] * inv1);
    *reinterpret_cast<float4*>(out + ((size_t)(0 * B + b) * N + n0 + g) * N + m0) = o0;
    *reinterpret_cast<float4*>(out + ((size_t)(1 * B + b) * N + n0 + g) * N + m0) = o1;
}

extern "C" void kernel_launch(void* const* d_in, const int* in_sizes, int n_in,
                              void* d_out, int out_size, void* d_ws, size_t ws_size,
                              hipStream_t stream) {
    const float* supports = (const float*)d_in[0];  // [E,N,N] fp32
    const float* uu       = (const float*)d_in[1];  // [E,N,K]
    const float* ss       = (const float*)d_in[2];  // [E,K]
    const float* vv       = (const float*)d_in[3];  // [E,N,K]
    const float* bias     = (const float*)d_in[4];  // [E,K]
    const float* inp      = (const float*)d_in[5];  // [B,T,N,2]
    float* out = (float*)d_out;                     // [E,B,N,N] fp32

    float* sup   = (float*)d_ws;                // 2 MiB
    float* nodes = sup + (size_t)E * N * N;     // 1.5 MiB

    k_prep<<<2 * (N / NB) + (B * N) / 512, 512, 0, stream>>>(
        supports, uu, ss, vv, bias, inp, sup, nodes);
    k_main<<<B * (N / NB), 512, 0, stream>>>(sup, nodes, out);
}

// Round 6
// 167.844 us; speedup vs baseline: 1.1318x; 1.1318x over previous
//
#include <hip/hip_runtime.h>

#define E 2
#define N 512
#define B 64
#define T 12
#define K 64
#define NBR 8   // rows per wave in k_main
#define RPB 32  // rows per block (4 waves)

// ---- DPP wave-64 sum (VALU pipe, no DS traffic), broadcast via readlane(63)
template<int CTRL, int RM>
__device__ __forceinline__ float dpp_add(float x) {
    int y = __builtin_amdgcn_update_dpp(0, __float_as_int(x), CTRL, RM, 0xf, true);
    return x + __int_as_float(y);
}
__device__ __forceinline__ float wave_sum64(float x) {
    x = dpp_add<0x111, 0xf>(x);   // row_shr:1
    x = dpp_add<0x112, 0xf>(x);   // row_shr:2
    x = dpp_add<0x114, 0xf>(x);   // row_shr:4
    x = dpp_add<0x118, 0xf>(x);   // row_shr:8
    x = dpp_add<0x142, 0xa>(x);   // row_bcast:15
    x = dpp_add<0x143, 0xc>(x);   // row_bcast:31
    return __int_as_float(__builtin_amdgcn_readlane(__float_as_int(x), 63));
}

// blocks [0,256): sup (4 n-rows/block); blocks [256,320): nodes for b=blk-256,
// written BOTH row-major (anchor s_loads) and transposed (coalesced col loads).
__global__ __launch_bounds__(512)
void k_prep(const float* __restrict__ supports, const float* __restrict__ uu,
            const float* __restrict__ ss, const float* __restrict__ vv,
            const float* __restrict__ bias, const float* __restrict__ inp,
            float* __restrict__ sup, float* __restrict__ nodes,
            float* __restrict__ nodesT) {
    const int blk = blockIdx.x, tid = threadIdx.x;
    if (blk < 256) {
        const int e = blk >> 7;
        const int n0 = (blk & 127) * 4;
        __shared__ float uls[4][K];
        if (tid < 4 * K) {
            const int j = tid >> 6, k = tid & 63;
            float bb = bias[e * K + k];
            float sp_ = (bb > 0.f) ? (bb + log1pf(expf(-bb))) : log1pf(expf(bb));
            uls[j][k] = uu[(size_t)(e * N + n0 + j) * K + k] * ss[e * K + k] * sp_;
        }
        __syncthreads();
        const int m = tid;
        const float4* vp = reinterpret_cast<const float4*>(vv + (size_t)(e * N + m) * K);
        float accs[4] = {0.f, 0.f, 0.f, 0.f};
#pragma unroll
        for (int i = 0; i < 16; ++i) {
            float4 q = vp[i];
#pragma unroll
            for (int j = 0; j < 4; ++j) {
                const float* w = &uls[j][i * 4];
                accs[j] += w[0] * q.x + w[1] * q.y + w[2] * q.z + w[3] * q.w;
            }
        }
#pragma unroll
        for (int j = 0; j < 4; ++j) {
            const size_t o = (size_t)(e * N + n0 + j) * N + m;
            sup[o] = accs[j] + supports[o];
        }
    } else {
        const int b = blk - 256;   // one block per batch
        const int n = tid;
        float x[T];
        float sq = 0.f;
#pragma unroll
        for (int t = 0; t < T; ++t) {
            float xv = inp[((size_t)(b * T + t) * N + n) * 2];
            x[t] = xv;
            sq += xv * xv;
        }
        float inv = 1.f / fmaxf(sqrtf(sq), 1e-12f);
#pragma unroll
        for (int t = 0; t < T; ++t) {
            float xv = x[t] * inv;
            nodes[((size_t)(b * N) + n) * T + t] = xv;     // row-major
            nodesT[((size_t)(b * T) + t) * N + n] = xv;    // transposed (coalesced)
        }
    }
}

// One wave handles 8 output rows x 512 cols. Lane owns 8 columns (regs),
// loops over anchor rows (wave-uniform s_loads). Zero LDS, zero barriers.
__global__ __launch_bounds__(256)
void k_main(const float* __restrict__ sup, const float* __restrict__ nodes,
            const float* __restrict__ nodesT, float* __restrict__ out) {
    const int bi = blockIdx.x;                    // B * (N/RPB) = 1024
    const int b = bi >> 4;
    const int wave = __builtin_amdgcn_readfirstlane((int)threadIdx.x >> 6);
    const int lane = threadIdx.x & 63;
    const int n0 = (bi & 15) * RPB + wave * NBR;
    const int m0 = lane * 8;

    // 8 columns x 12 t, coalesced from transposed layout (loaded once per wave)
    float x[T][8];
#pragma unroll
    for (int t = 0; t < T; ++t) {
        const float* cp = nodesT + ((size_t)(b * T) + t) * N + m0;
        float4 c0 = *reinterpret_cast<const float4*>(cp);
        float4 c1 = *reinterpret_cast<const float4*>(cp + 4);
        x[t][0] = c0.x; x[t][1] = c0.y; x[t][2] = c0.z; x[t][3] = c0.w;
        x[t][4] = c1.x; x[t][5] = c1.y; x[t][6] = c1.z; x[t][7] = c1.w;
    }

#pragma unroll
    for (int j = 0; j < NBR; ++j) {
        const int n = n0 + j;
        const float* ap = nodes + ((size_t)(b * N) + n) * T;  // wave-uniform
        float4 a0 = *reinterpret_cast<const float4*>(ap);
        float4 a1 = *reinterpret_cast<const float4*>(ap + 4);
        float4 a2 = *reinterpret_cast<const float4*>(ap + 8);
        float a[T] = {a0.x, a0.y, a0.z, a0.w, a1.x, a1.y, a1.z, a1.w,
                      a2.x, a2.y, a2.z, a2.w};

        const float* s0p = sup + (size_t)n * N + m0;
        const float* s1p = s0p + (size_t)N * N;
        float4 sA = *reinterpret_cast<const float4*>(s0p);
        float4 sB = *reinterpret_cast<const float4*>(s0p + 4);
        float4 sC = *reinterpret_cast<const float4*>(s1p);
        float4 sD = *reinterpret_cast<const float4*>(s1p + 4);
        float sp0[8] = {sA.x, sA.y, sA.z, sA.w, sB.x, sB.y, sB.z, sB.w};
        float sp1[8] = {sC.x, sC.y, sC.z, sC.w, sD.x, sD.y, sD.z, sD.w};

        float v0[8], v1[8];
        float p0 = 0.f, p1 = 0.f;
#pragma unroll
        for (int k = 0; k < 8; ++k) {
            float dot = 0.f;
#pragma unroll
            for (int t = 0; t < T; ++t) dot = fmaf(x[t][k], a[t], dot);
            // rows are unit-norm: d2 = |xn|^2+|xm|^2-2 dot = 2-2dot (clamped)
            float d2 = fmaxf(2.f - 2.f * dot, 0.f);
            float f = __expf(-sqrtf(d2)) + 1.f;
            v0[k] = fmaxf(sp0[k] * f, 0.f);
            v1[k] = fmaxf(sp1[k] * f, 0.f);
            p0 += v0[k];
            p1 += v1[k];
        }
        float inv0 = 1.f / fmaxf(wave_sum64(p0), 1e-12f);
        float inv1 = 1.f / fmaxf(wave_sum64(p1), 1e-12f);

        float* o0 = out + ((size_t)(b * N) + n) * N + m0;
        float* o1 = o0 + (size_t)B * N * N;
        *reinterpret_cast<float4*>(o0) =
            make_float4(v0[0] * inv0, v0[1] * inv0, v0[2] * inv0, v0[3] * inv0);
        *reinterpret_cast<float4*>(o0 + 4) =
            make_float4(v0[4] * inv0, v0[5] * inv0, v0[6] * inv0, v0[7] * inv0);
        *reinterpret_cast<float4*>(o1) =
            make_float4(v1[0] * inv1, v1[1] * inv1, v1[2] * inv1, v1[3] * inv1);
        *reinterpret_cast<float4*>(o1 + 4) =
            make_float4(v1[4] * inv1, v1[5] * inv1, v1[6] * inv1, v1[7] * inv1);
    }
}

extern "C" void kernel_launch(void* const* d_in, const int* in_sizes, int n_in,
                              void* d_out, int out_size, void* d_ws, size_t ws_size,
                              hipStream_t stream) {
    const float* supports = (const float*)d_in[0];  // [E,N,N] fp32
    const float* uu       = (const float*)d_in[1];  // [E,N,K]
    const float* ss       = (const float*)d_in[2];  // [E,K]
    const float* vv       = (const float*)d_in[3];  // [E,N,K]
    const float* bias     = (const float*)d_in[4];  // [E,K]
    const float* inp      = (const float*)d_in[5];  // [B,T,N,2]
    float* out = (float*)d_out;                     // [E,B,N,N] fp32

    float* sup    = (float*)d_ws;                       // 2 MiB
    float* nodes  = sup + (size_t)E * N * N;            // 1.5 MiB
    float* nodesT = nodes + (size_t)B * N * T;          // 1.5 MiB

    k_prep<<<256 + B, 512, 0, stream>>>(supports, uu, ss, vv, bias, inp,
                                        sup, nodes, nodesT);
    k_main<<<B * (N / RPB), 256, 0, stream>>>(sup, nodes, nodesT, out);
}